// Round 1
// baseline (4892.647 us; speedup 1.0000x reference)
//
#include <hip/hip_runtime.h>
#include <hip/hip_bf16.h>

// EntityAwareLSTMLayer: B=1024, T=365, DYN=32, STATIC=27, U=256 (3U=768 gates)
// Round 1: correct fp32 persistent baseline.
//   grid = 256 WGs (4 batch rows each), block = 256 threads (thread u owns
//   gate columns u / u+256 / u+512 = f/o/g of hidden unit u).
//   h in LDS (broadcast K-loop reads), c & i_gate in registers.
//   Weights streamed fp32 from L2 each step -> predicted L2-BW-bound ~2.4ms.

#define B_TOTAL  1024
#define T_STEPS  365
#define DYNF     32
#define STATF    27
#define UNITS    256
#define G3       768
#define BB       4   // batch rows per workgroup

__device__ __forceinline__ float fast_sigmoid(float x) {
    return 1.0f / (1.0f + __expf(-x));
}
__device__ __forceinline__ float fast_tanh(float x) {
    // tanh(x) = 1 - 2/(1+exp(2x)); saturates correctly at +/-inf in fp32
    return 1.0f - 2.0f / (1.0f + __expf(2.0f * x));
}

__global__ __launch_bounds__(256) void lstm_persist(
    const float* __restrict__ x_dyn,   // [1024][365][32]
    const float* __restrict__ x_sta,   // [1024][27]
    const float* __restrict__ w_ih,    // [32][768]
    const float* __restrict__ w_hh,    // [256][768]
    const float* __restrict__ w_sh,    // [27][256]
    const float* __restrict__ bias,    // [768]
    const float* __restrict__ bias_s,  // [256]
    float* __restrict__ out)           // [1024][256]
{
    const int u  = threadIdx.x;        // hidden unit this thread owns
    const int b0 = blockIdx.x * BB;    // first batch row of this WG

    __shared__ float h_s[BB][UNITS];
    __shared__ float xt_s[BB][DYNF];

    // per-gate biases for my columns
    const float bf = bias[u];
    const float bo = bias[u + UNITS];
    const float bg = bias[u + 2 * UNITS];

    // entity-aware static input gate: i = sigmoid(x_static @ w_sh + bias_s)
    float ig[BB];
    #pragma unroll
    for (int b = 0; b < BB; ++b) {
        float s = bias_s[u];
        #pragma unroll
        for (int j = 0; j < STATF; ++j)
            s += x_sta[(b0 + b) * STATF + j] * w_sh[j * UNITS + u];
        ig[b] = fast_sigmoid(s);
    }

    float c[BB];
    #pragma unroll
    for (int b = 0; b < BB; ++b) {
        c[b] = 0.0f;
        h_s[b][u] = 0.0f;
    }
    __syncthreads();

    for (int t = 0; t < T_STEPS; ++t) {
        // stage x_t for my 4 batch rows: 4*32 = 128 loads
        if (u < BB * DYNF) {
            const int b = u >> 5, j = u & 31;
            xt_s[b][j] = x_dyn[((size_t)(b0 + b) * T_STEPS + t) * DYNF + j];
        }
        __syncthreads();  // xt_s ready; also makes prev-step h_s writes visible

        float aF[BB], aO[BB], aG[BB];
        #pragma unroll
        for (int b = 0; b < BB; ++b) { aF[b] = bf; aO[b] = bo; aG[b] = bg; }

        // input contribution: gx = x_t @ w_ih
        #pragma unroll 4
        for (int j = 0; j < DYNF; ++j) {
            const float wf = w_ih[j * G3 + u];
            const float wo = w_ih[j * G3 + UNITS + u];
            const float wg = w_ih[j * G3 + 2 * UNITS + u];
            const float x0 = xt_s[0][j], x1 = xt_s[1][j],
                        x2 = xt_s[2][j], x3 = xt_s[3][j];
            aF[0] += x0 * wf; aF[1] += x1 * wf; aF[2] += x2 * wf; aF[3] += x3 * wf;
            aO[0] += x0 * wo; aO[1] += x1 * wo; aO[2] += x2 * wo; aO[3] += x3 * wo;
            aG[0] += x0 * wg; aG[1] += x1 * wg; aG[2] += x2 * wg; aG[3] += x3 * wg;
        }

        // recurrent contribution: h @ w_hh (h broadcast from LDS)
        #pragma unroll 8
        for (int j = 0; j < UNITS; ++j) {
            const float wf = w_hh[j * G3 + u];
            const float wo = w_hh[j * G3 + UNITS + u];
            const float wg = w_hh[j * G3 + 2 * UNITS + u];
            const float h0 = h_s[0][j], h1 = h_s[1][j],
                        h2 = h_s[2][j], h3 = h_s[3][j];
            aF[0] += h0 * wf; aF[1] += h1 * wf; aF[2] += h2 * wf; aF[3] += h3 * wf;
            aO[0] += h0 * wo; aO[1] += h1 * wo; aO[2] += h2 * wo; aO[3] += h3 * wo;
            aG[0] += h0 * wg; aG[1] += h1 * wg; aG[2] += h2 * wg; aG[3] += h3 * wg;
        }
        __syncthreads();  // all h_s reads done before overwrite

        // LSTM cell update (thread-aligned: unit u, rows b0..b0+3)
        #pragma unroll
        for (int b = 0; b < BB; ++b) {
            c[b] = fast_sigmoid(aF[b]) * c[b] + ig[b] * fast_tanh(aG[b]);
            h_s[b][u] = fast_sigmoid(aO[b]) * fast_tanh(c[b]);
        }
        __syncthreads();
    }

    #pragma unroll
    for (int b = 0; b < BB; ++b)
        out[(size_t)(b0 + b) * UNITS + u] = h_s[b][u];
}

extern "C" void kernel_launch(void* const* d_in, const int* in_sizes, int n_in,
                              void* d_out, int out_size, void* d_ws, size_t ws_size,
                              hipStream_t stream) {
    const float* x_dyn  = (const float*)d_in[0];
    const float* x_sta  = (const float*)d_in[1];
    const float* w_ih   = (const float*)d_in[2];
    const float* w_hh   = (const float*)d_in[3];
    const float* w_sh   = (const float*)d_in[4];
    const float* bias   = (const float*)d_in[5];
    const float* bias_s = (const float*)d_in[6];
    float* out = (float*)d_out;

    dim3 grid(B_TOTAL / BB);   // 256 workgroups, 1 per CU
    dim3 block(UNITS);         // 256 threads
    lstm_persist<<<grid, block, 0, stream>>>(x_dyn, x_sta, w_ih, w_hh, w_sh,
                                             bias, bias_s, out);
}

// Round 2
// 2066.581 us; speedup vs baseline: 2.3675x; 2.3675x over previous
//
#include <hip/hip_runtime.h>
#include <hip/hip_bf16.h>

// EntityAwareLSTMLayer: B=1024, T=365, DYN=32, STATIC=27, U=256 (3U=768)
// Round 2: bf16 MFMA recurrence with identity-residual split.
//   gates = [h|x_t](bf16) @ Wpack(bf16) + bias + h_prev(fp32 identity term)
//   Wpack = [[W_hh - eye3tile]; [W_ih]]  (residual ~0.02 scale -> bf16 error tiny;
//   dominant identity path stays exact fp32).
//   64 WGs x 1024 thr (16 waves, M=16 batch rows each). Per step:
//   9 A-frag ds_reads + 27 MFMA(16x16x32) per wave, C->LDS, cell update in regs.

typedef short short8 __attribute__((ext_vector_type(8)));
typedef float f32x4 __attribute__((ext_vector_type(4)));

#define T_STEPS 365
#define UNITS   256
#define G3      768
#define KTOT    288   // 256 (h) + 32 (x)
#define KC      36    // K chunks of 8 bf16
#define MROWS   16    // batch rows per WG
#define NWGS    64

__device__ __forceinline__ unsigned short f2bf(float x) {
    union { float f; unsigned u; } v; v.f = x;
    return (unsigned short)((v.u + 0x7FFFu + ((v.u >> 16) & 1u)) >> 16);
}
__device__ __forceinline__ float sigmoidf_(float x) {
    return 1.0f / (1.0f + __expf(-x));
}
__device__ __forceinline__ float tanhf_(float x) {
    return 1.0f - 2.0f / (1.0f + __expf(2.0f * x));
}

// Pack Wpack[k=0..287][n=0..767] -> bf16 B-fragment layout:
//   element (k,n) at wp[((k>>3)*768 + n)*8 + (k&7)]
__global__ __launch_bounds__(256) void pack_weights(
    const float* __restrict__ w_ih, const float* __restrict__ w_hh,
    unsigned short* __restrict__ wp)
{
    int idx = blockIdx.x * 256 + threadIdx.x;
    if (idx >= KTOT * G3) return;
    int k = idx / G3, n = idx - k * G3;
    float v;
    if (k < UNITS) {
        v = w_hh[k * G3 + n];
        if ((n & 255) == k) v -= 1.0f;   // subtract eye3 tile
    } else {
        v = w_ih[(k - UNITS) * G3 + n];
    }
    wp[(((k >> 3) * G3) + n) * 8 + (k & 7)] = f2bf(v);
}

__global__ __launch_bounds__(1024, 4) void lstm_mfma(
    const float* __restrict__ x_dyn,   // [1024][365][32]
    const float* __restrict__ x_sta,   // [1024][27]
    const unsigned short* __restrict__ wp,  // packed bf16 [36][768][8]
    const float* __restrict__ w_sh,    // [27][256]
    const float* __restrict__ bias,    // [768]
    const float* __restrict__ bias_s,  // [256]
    float* __restrict__ out)           // [1024][256]
{
    __shared__ unsigned short A_s[KC][17][8];  // [kchunk][row(+1 pad)][8] bf16
    __shared__ float gates_s[MROWS][769];      // +1 pad vs 768
    __shared__ float h_s[MROWS][UNITS];        // fp32 h for exact identity term

    const int tid = threadIdx.x;
    const int b0  = blockIdx.x * MROWS;

    // zero-init h chunks of A (kc 0..31) and h_s; x chunks written each step
    for (int i = tid; i < 32 * 17 * 8; i += 1024) ((unsigned short*)A_s)[i] = 0;
    for (int i = tid; i < MROWS * UNITS; i += 1024) ((float*)h_s)[i] = 0.0f;

    // ---- cell-update mapping: thread owns unit u for 4 batch rows ----
    const int u    = tid & 255;
    const int bset = tid >> 8;            // 0..3
    const float bf_ = bias[u], bo_ = bias[UNITS + u], bg_ = bias[2 * UNITS + u];

    float ig[4], cc[4], hn[4];
    #pragma unroll
    for (int i = 0; i < 4; ++i) {
        const int b = bset * 4 + i;
        float s = bias_s[u];
        #pragma unroll
        for (int j = 0; j < 27; ++j)
            s += x_sta[(b0 + b) * 27 + j] * w_sh[j * UNITS + u];
        ig[i] = sigmoidf_(s);
        cc[i] = 0.0f; hn[i] = 0.0f;
    }

    // ---- MFMA mapping ----
    const int lane = tid & 63;
    const int wv   = tid >> 6;            // wave 0..15, owns cols wv*48..+47
    const int mm   = lane & 15;           // A row / B col / C col
    const int qq   = lane >> 4;           // quad

    // x_t prefetch (threads 0..511: one fp32 each)
    const int xb = tid >> 5, xj = tid & 31;
    float xr = 0.0f;
    if (tid < 512) xr = x_dyn[((size_t)(b0 + xb) * T_STEPS + 0) * 32 + xj];

    for (int t = 0; t < T_STEPS; ++t) {
        // stage x_t into A chunks 32..35
        if (tid < 512)
            A_s[32 + (xj >> 3)][xb][xj & 7] = f2bf(xr);
        __syncthreads();   // B1: A ([h_{t-1} | x_t]) ready

        // load 9 A-fragments (reused across 3 N-tiles)
        short8 a[9];
        #pragma unroll
        for (int ks = 0; ks < 9; ++ks)
            a[ks] = *(const short8*)&A_s[ks * 4 + qq][mm][0];

        #pragma unroll
        for (int nt = 0; nt < 3; ++nt) {
            const int n = wv * 48 + nt * 16 + mm;
            f32x4 acc = {0.f, 0.f, 0.f, 0.f};
            #pragma unroll
            for (int ks = 0; ks < 9; ++ks) {
                short8 bfr = *(const short8*)(wp + (((ks * 4 + qq) * G3) + n) * 8);
                acc = __builtin_amdgcn_mfma_f32_16x16x32_bf16(a[ks], bfr, acc, 0, 0, 0);
            }
            #pragma unroll
            for (int r = 0; r < 4; ++r)
                gates_s[qq * 4 + r][n] = acc[r];   // C: col=lane&15, row=q*4+r
        }

        // prefetch next x while MFMA results land
        if (tid < 512 && t + 1 < T_STEPS)
            xr = x_dyn[((size_t)(b0 + xb) * T_STEPS + (t + 1)) * 32 + xj];

        __syncthreads();   // B2: gates complete

        // cell update (reads gates_s,h_s; writes h_s + bf16 A chunks)
        #pragma unroll
        for (int i = 0; i < 4; ++i) {
            const int b = bset * 4 + i;
            const float hp = h_s[b][u];                    // exact identity term
            const float gf = gates_s[b][u]             + bf_ + hp;
            const float go = gates_s[b][UNITS + u]     + bo_ + hp;
            const float gg = gates_s[b][2 * UNITS + u] + bg_ + hp;
            const float f  = sigmoidf_(gf);
            const float o  = sigmoidf_(go);
            const float cn = f * cc[i] + ig[i] * tanhf_(gg);
            cc[i] = cn;
            const float h = o * tanhf_(cn);
            hn[i] = h;
            h_s[b][u] = h;
            A_s[u >> 3][b][u & 7] = f2bf(h);
        }
        // no barrier here: loop-top x-write touches disjoint chunks; B1 orders h
    }

    #pragma unroll
    for (int i = 0; i < 4; ++i)
        out[(size_t)(b0 + bset * 4 + i) * UNITS + u] = hn[i];
}

extern "C" void kernel_launch(void* const* d_in, const int* in_sizes, int n_in,
                              void* d_out, int out_size, void* d_ws, size_t ws_size,
                              hipStream_t stream) {
    const float* x_dyn  = (const float*)d_in[0];
    const float* x_sta  = (const float*)d_in[1];
    const float* w_ih   = (const float*)d_in[2];
    const float* w_hh   = (const float*)d_in[3];
    const float* w_sh   = (const float*)d_in[4];
    const float* bias   = (const float*)d_in[5];
    const float* bias_s = (const float*)d_in[6];
    float* out = (float*)d_out;
    unsigned short* wp = (unsigned short*)d_ws;   // needs 288*768*2 = 442 KB

    pack_weights<<<(KTOT * G3 + 255) / 256, 256, 0, stream>>>(w_ih, w_hh, wp);
    lstm_mfma<<<NWGS, 1024, 0, stream>>>(x_dyn, x_sta, wp, w_sh, bias, bias_s, out);
}

// Round 3
// 1941.504 us; speedup vs baseline: 2.5200x; 1.0644x over previous
//
#include <hip/hip_runtime.h>
#include <hip/hip_bf16.h>

// EntityAwareLSTMLayer: B=1024, T=365, DYN=32, STATIC=27, U=256 (3U=768)
// Round 3: register-resident weights + in-register cell state.
//   - Wpack (bf16, identity-residual: [[W_hh - eye3]; [W_ih]]) preloaded into
//     27 B-fragments per wave (108 regs -> AGPR-friendly), NO per-step global.
//   - Wave wv owns units wv*16..wv*16+15 for ALL 3 gates (N-tiles at
//     {u, 256+u, 512+u}) -> f/o/g of a (row,unit) land in one lane; c, h_prev
//     (fp32 identity term) and i_gate stay in registers forever.
//   - A = [h|x] bf16 in LDS, double-buffered -> ONE barrier per step.
//   64 WGs x 1024 thr (16 waves, 16 batch rows per WG).

typedef short short8 __attribute__((ext_vector_type(8)));
typedef float f32x4 __attribute__((ext_vector_type(4)));

#define T_STEPS 365
#define UNITS   256
#define G3      768
#define KTOT    288   // 256 (h) + 32 (x)
#define MROWS   16
#define NWGS    64

__device__ __forceinline__ unsigned short f2bf(float x) {
    union { float f; unsigned u; } v; v.f = x;
    return (unsigned short)((v.u + 0x7FFFu + ((v.u >> 16) & 1u)) >> 16);
}
__device__ __forceinline__ float sigmoidf_(float x) {
    return 1.0f / (1.0f + __expf(-x));
}
__device__ __forceinline__ float tanhf_(float x) {
    return 1.0f - 2.0f / (1.0f + __expf(2.0f * x));
}

// Wpack[k=0..287][n=0..767] -> bf16 B-fragment layout:
//   element (k,n) at wp[((k>>3)*768 + n)*8 + (k&7)]
__global__ __launch_bounds__(256) void pack_weights(
    const float* __restrict__ w_ih, const float* __restrict__ w_hh,
    unsigned short* __restrict__ wp)
{
    int idx = blockIdx.x * 256 + threadIdx.x;
    if (idx >= KTOT * G3) return;
    int k = idx / G3, n = idx - k * G3;
    float v;
    if (k < UNITS) {
        v = w_hh[k * G3 + n];
        if ((n & 255) == k) v -= 1.0f;   // subtract eye3 tile
    } else {
        v = w_ih[(k - UNITS) * G3 + n];
    }
    wp[(((k >> 3) * G3) + n) * 8 + (k & 7)] = f2bf(v);
}

__global__ __launch_bounds__(1024) void lstm_mfma(
    const float* __restrict__ x_dyn,   // [1024][365][32]
    const float* __restrict__ x_sta,   // [1024][27]
    const unsigned short* __restrict__ wp,  // packed bf16 [36][768][8]
    const float* __restrict__ w_sh,    // [27][256]
    const float* __restrict__ bias,    // [768]
    const float* __restrict__ bias_s,  // [256]
    float* __restrict__ out)           // [1024][256]
{
    // A = [h (chunks 0..31) | x (chunks 32..35)], double-buffered.
    // element (row m, k) at Ab[buf][k>>3][m][k&7]; row dim padded 16->17.
    __shared__ unsigned short Ab[2][36][17][8];

    const int tid  = threadIdx.x;
    const int b0   = blockIdx.x * MROWS;
    const int lane = tid & 63;
    const int wv   = tid >> 6;          // wave 0..15
    const int mm   = lane & 15;
    const int qq   = lane >> 4;
    const int u    = wv * 16 + mm;      // unit this lane owns (C col & cell unit)

    // ---- preload 27 B-fragments (3 gates x 9 K-chunks), loop-invariant ----
    short8 bw[3][9];
    #pragma unroll
    for (int g = 0; g < 3; ++g)
        #pragma unroll
        for (int ks = 0; ks < 9; ++ks)
            bw[g][ks] = *(const short8*)(wp + ((size_t)(ks * 4 + qq) * G3 + g * UNITS + u) * 8);

    // zero h-chunks of buffer 0 (chunk-major layout: first 32*17*8 shorts)
    for (int i = tid; i < 32 * 17 * 8; i += 1024)
        ((unsigned short*)&Ab[0][0][0][0])[i] = 0;

    // ---- x staging: threads 0..511 own (row xb, feature xj) ----
    const int xb = tid >> 5, xj = tid & 31;
    float xr = 0.0f;
    if (tid < 512) {
        float x0 = x_dyn[((size_t)(b0 + xb) * T_STEPS + 0) * 32 + xj];
        Ab[0][32 + (xj >> 3)][xb][xj & 7] = f2bf(x0);
        xr = x_dyn[((size_t)(b0 + xb) * T_STEPS + 1) * 32 + xj];
    }

    // ---- per-lane cell state: rows qq*4+r, unit u ----
    const float bf_ = bias[u], bo_ = bias[UNITS + u], bg_ = bias[2 * UNITS + u];
    float ig[4], cc[4], hp[4];
    #pragma unroll
    for (int r = 0; r < 4; ++r) {
        const int row = qq * 4 + r;
        float s = bias_s[u];
        #pragma unroll
        for (int j = 0; j < 27; ++j)
            s += x_sta[(b0 + row) * 27 + j] * w_sh[j * UNITS + u];
        ig[r] = sigmoidf_(s);
        cc[r] = 0.0f; hp[r] = 0.0f;
    }

    const int kcH = u >> 3, koH = u & 7;   // h-write slot for unit u

    for (int t = 0; t < T_STEPS; ++t) {
        const int p = t & 1;
        __syncthreads();   // buf[p] (h_t | x_t) complete; buf[p^1] free

        short8 a[9];
        #pragma unroll
        for (int ks = 0; ks < 9; ++ks)
            a[ks] = *(const short8*)&Ab[p][ks * 4 + qq][mm][0];

        f32x4 acc0 = {0.f,0.f,0.f,0.f}, acc1 = {0.f,0.f,0.f,0.f}, acc2 = {0.f,0.f,0.f,0.f};
        #pragma unroll
        for (int ks = 0; ks < 9; ++ks) {
            acc0 = __builtin_amdgcn_mfma_f32_16x16x32_bf16(a[ks], bw[0][ks], acc0, 0, 0, 0);
            acc1 = __builtin_amdgcn_mfma_f32_16x16x32_bf16(a[ks], bw[1][ks], acc1, 0, 0, 0);
            acc2 = __builtin_amdgcn_mfma_f32_16x16x32_bf16(a[ks], bw[2][ks], acc2, 0, 0, 0);
        }

        // cell update fully in registers; write h_{t+1} bf16 into buf[p^1]
        #pragma unroll
        for (int r = 0; r < 4; ++r) {
            const float h0 = hp[r];                    // exact fp32 identity term
            const float f  = sigmoidf_(acc0[r] + bf_ + h0);
            const float o  = sigmoidf_(acc1[r] + bo_ + h0);
            const float g  = tanhf_  (acc2[r] + bg_ + h0);
            const float cn = f * cc[r] + ig[r] * g;
            cc[r] = cn;
            const float hn = o * tanhf_(cn);
            hp[r] = hn;
            Ab[p ^ 1][kcH][qq * 4 + r][koH] = f2bf(hn);
        }

        // stage x_{t+1} into buf[p^1]; prefetch x_{t+2}
        if (tid < 512) {
            Ab[p ^ 1][32 + (xj >> 3)][xb][xj & 7] = f2bf(xr);
            if (t + 2 < T_STEPS)
                xr = x_dyn[((size_t)(b0 + xb) * T_STEPS + (t + 2)) * 32 + xj];
        }
    }

    #pragma unroll
    for (int r = 0; r < 4; ++r)
        out[(size_t)(b0 + qq * 4 + r) * UNITS + u] = hp[r];
}

extern "C" void kernel_launch(void* const* d_in, const int* in_sizes, int n_in,
                              void* d_out, int out_size, void* d_ws, size_t ws_size,
                              hipStream_t stream) {
    const float* x_dyn  = (const float*)d_in[0];
    const float* x_sta  = (const float*)d_in[1];
    const float* w_ih   = (const float*)d_in[2];
    const float* w_hh   = (const float*)d_in[3];
    const float* w_sh   = (const float*)d_in[4];
    const float* bias   = (const float*)d_in[5];
    const float* bias_s = (const float*)d_in[6];
    float* out = (float*)d_out;
    unsigned short* wp = (unsigned short*)d_ws;   // 288*768*2 = 442 KB scratch

    pack_weights<<<(KTOT * G3 + 255) / 256, 256, 0, stream>>>(w_ih, w_hh, wp);
    lstm_mfma<<<NWGS, 1024, 0, stream>>>(x_dyn, x_sta, wp, w_sh, bias, bias_s, out);
}

// Round 4
// 1279.075 us; speedup vs baseline: 3.8251x; 1.5179x over previous
//
#include <hip/hip_runtime.h>
#include <hip/hip_bf16.h>

// EntityAwareLSTMLayer: B=1024, T=365, DYN=32, STATIC=27, U=256 (3U=768)
// Round 4: truly register-resident W_hh residual.
//   - 128 WGs x 512 thr (8 waves, 2/SIMD, 256-reg budget via launch_bounds(512,2)).
//   - Each wave owns 32 units x 3 gates: 48 B-frags = 192 regs, loaded ONCE.
//   - W_ih (48 KB) stays in LDS; A=[h|x] bf16 double-buffered, 1 barrier/step.
//   - M=8 rows/WG; C-layout rows 0..7 live in quads 0-1 -> __shfl(lane^32)
//     spreads cells to quads 2-3 so all 64 lanes do 4 cell updates each.
//   - A row stride 296 shorts = 4*37 dwords -> <=2-way LDS conflicts (free).

typedef short short8 __attribute__((ext_vector_type(8)));
typedef float f32x4 __attribute__((ext_vector_type(4)));

#define T_STEPS 365
#define UNITS   256
#define G3      768
#define KTOT    288   // 256 (h) + 32 (x)
#define MROWS   8
#define NWGS    128
#define AP      296   // padded A row length in shorts (592 B = 4*37 dwords)

__device__ __forceinline__ unsigned short f2bf(float x) {
    union { float f; unsigned u; } v; v.f = x;
    return (unsigned short)((v.u + 0x7FFFu + ((v.u >> 16) & 1u)) >> 16);
}
__device__ __forceinline__ float sigmoidf_(float x) {
    return 1.0f / (1.0f + __expf(-x));
}
__device__ __forceinline__ float tanhf_(float x) {
    return 1.0f - 2.0f / (1.0f + __expf(2.0f * x));
}

// Wpack[k=0..287][n=0..767] -> bf16 B-fragment layout:
//   element (k,n) at wp[((k>>3)*768 + n)*8 + (k&7)]
__global__ __launch_bounds__(256) void pack_weights(
    const float* __restrict__ w_ih, const float* __restrict__ w_hh,
    unsigned short* __restrict__ wp)
{
    int idx = blockIdx.x * 256 + threadIdx.x;
    if (idx >= KTOT * G3) return;
    int k = idx / G3, n = idx - k * G3;
    float v;
    if (k < UNITS) {
        v = w_hh[k * G3 + n];
        if ((n & 255) == k) v -= 1.0f;   // subtract eye3 tile
    } else {
        v = w_ih[(k - UNITS) * G3 + n];
    }
    wp[(((k >> 3) * G3) + n) * 8 + (k & 7)] = f2bf(v);
}

__global__ __launch_bounds__(512, 2) void lstm_mfma(
    const float* __restrict__ x_dyn,   // [1024][365][32]
    const float* __restrict__ x_sta,   // [1024][27]
    const unsigned short* __restrict__ wp,  // packed bf16 [36][768][8]
    const float* __restrict__ w_sh,    // [27][256]
    const float* __restrict__ bias,    // [768]
    const float* __restrict__ bias_s,  // [256]
    float* __restrict__ out)           // [1024][256]
{
    __shared__ unsigned short A_s[2][16][AP];       // ~18.9 KB
    __shared__ unsigned short wih_s[4 * G3 * 8];    // 48 KB: W_ih chunks 32..35

    const int tid  = threadIdx.x;
    const int b0   = blockIdx.x * MROWS;
    const int lane = tid & 63;
    const int wv   = tid >> 6;          // wave 0..7, owns units wv*32..+31
    const int mm   = lane & 15;
    const int qq   = lane >> 4;

    // ---- preload 48 B-fragments (8 kchunks x 3 gates x 2 ugroups) = 192 regs ----
    short8 bw[8][3][2];
    #pragma unroll
    for (int ks = 0; ks < 8; ++ks)
        #pragma unroll
        for (int g = 0; g < 3; ++g)
            #pragma unroll
            for (int h = 0; h < 2; ++h)
                bw[ks][g][h] = *(const short8*)(wp +
                    ((size_t)(ks * 4 + qq) * G3 + g * UNITS + wv * 32 + h * 16 + mm) * 8);

    // W_ih fragment region (chunks 32..35) -> LDS
    {
        const short8* src = (const short8*)(wp + (size_t)32 * G3 * 8);
        short8* dst = (short8*)wih_s;
        for (int i = tid; i < 4 * G3; i += 512) dst[i] = src[i];
    }

    // zero both A buffers (rows 8..15 stay zero forever)
    for (int i = tid; i < 2 * 16 * AP; i += 512)
        ((unsigned short*)A_s)[i] = 0;
    __syncthreads();

    // stage x_0, prefetch x_1 (threads 0..255: one (row, feature) each)
    float xr = 0.0f;
    if (tid < MROWS * 32) {
        const int row = tid >> 5, j = tid & 31;
        A_s[0][row][UNITS + j] =
            f2bf(x_dyn[((size_t)(b0 + row) * T_STEPS + 0) * 32 + j]);
        xr = x_dyn[((size_t)(b0 + row) * T_STEPS + 1) * 32 + j];
    }

    // ---- cell mapping: lane handles units {u0,u1}, rows {row0,row0+1} ----
    const int u0   = wv * 32 + mm;
    const int u1   = u0 + 16;
    const int row0 = (qq & 1) * 4 + ((qq & 2) ? 2 : 0);  // qq: 0->0, 1->4, 2->2, 3->6

    const float bfv[2] = { bias[u0],             bias[u1] };
    const float bov[2] = { bias[UNITS + u0],     bias[UNITS + u1] };
    const float bgv[2] = { bias[2 * UNITS + u0], bias[2 * UNITS + u1] };

    float ig[4], cc[4], hp[4];
    #pragma unroll
    for (int h = 0; h < 2; ++h)
        #pragma unroll
        for (int r = 0; r < 2; ++r) {
            const int u = h ? u1 : u0;
            const int row = row0 + r;
            float s = bias_s[u];
            #pragma unroll
            for (int j = 0; j < 27; ++j)
                s += x_sta[(b0 + row) * 27 + j] * w_sh[j * UNITS + u];
            ig[h * 2 + r] = sigmoidf_(s);
            cc[h * 2 + r] = 0.0f; hp[h * 2 + r] = 0.0f;
        }

    for (int t = 0; t < T_STEPS; ++t) {
        const int p = t & 1;
        __syncthreads();   // A[p] = [h_t | x_t] complete; A[p^1] free

        const unsigned short* Ap = &A_s[p][0][0];
        const int abase = mm * AP;

        #pragma unroll
        for (int h = 0; h < 2; ++h) {
            f32x4 ac0 = {0.f,0.f,0.f,0.f}, ac1 = {0.f,0.f,0.f,0.f}, ac2 = {0.f,0.f,0.f,0.f};
            #pragma unroll
            for (int ks = 0; ks < 8; ++ks) {
                const short8 a = *(const short8*)(Ap + abase + ks * 32 + qq * 8);
                ac0 = __builtin_amdgcn_mfma_f32_16x16x32_bf16(a, bw[ks][0][h], ac0, 0, 0, 0);
                ac1 = __builtin_amdgcn_mfma_f32_16x16x32_bf16(a, bw[ks][1][h], ac1, 0, 0, 0);
                ac2 = __builtin_amdgcn_mfma_f32_16x16x32_bf16(a, bw[ks][2][h], ac2, 0, 0, 0);
            }
            {   // x-contribution chunk (k=256..287), B from LDS
                const short8 a = *(const short8*)(Ap + abase + UNITS + qq * 8);
                const int wb = (qq * G3 + wv * 32 + h * 16 + mm) * 8;
                const short8 bx0 = *(const short8*)(wih_s + wb);
                const short8 bx1 = *(const short8*)(wih_s + wb + UNITS * 8);
                const short8 bx2 = *(const short8*)(wih_s + wb + 2 * UNITS * 8);
                ac0 = __builtin_amdgcn_mfma_f32_16x16x32_bf16(a, bx0, ac0, 0, 0, 0);
                ac1 = __builtin_amdgcn_mfma_f32_16x16x32_bf16(a, bx1, ac1, 0, 0, 0);
                ac2 = __builtin_amdgcn_mfma_f32_16x16x32_bf16(a, bx2, ac2, 0, 0, 0);
            }

            // balance rows across quads: quads 2,3 take partner's r=2,3
            const bool lo = (qq < 2);
            float gf0, gf1, go0, go1, gg0, gg1;
            { const float v2 = __shfl(ac0[2], lane ^ 32, 64);
              const float v3 = __shfl(ac0[3], lane ^ 32, 64);
              gf0 = lo ? ac0[0] : v2;  gf1 = lo ? ac0[1] : v3; }
            { const float v2 = __shfl(ac1[2], lane ^ 32, 64);
              const float v3 = __shfl(ac1[3], lane ^ 32, 64);
              go0 = lo ? ac1[0] : v2;  go1 = lo ? ac1[1] : v3; }
            { const float v2 = __shfl(ac2[2], lane ^ 32, 64);
              const float v3 = __shfl(ac2[3], lane ^ 32, 64);
              gg0 = lo ? ac2[0] : v2;  gg1 = lo ? ac2[1] : v3; }

            const int u = h ? u1 : u0;
            #pragma unroll
            for (int r = 0; r < 2; ++r) {
                const int ci = h * 2 + r;
                const float h0  = hp[ci];                     // exact fp32 identity term
                const float gfv = (r ? gf1 : gf0) + bfv[h] + h0;
                const float gov = (r ? go1 : go0) + bov[h] + h0;
                const float ggv = (r ? gg1 : gg0) + bgv[h] + h0;
                const float f   = sigmoidf_(gfv);
                const float o   = sigmoidf_(gov);
                const float gt  = tanhf_(ggv);
                const float cn  = f * cc[ci] + ig[ci] * gt;
                cc[ci] = cn;
                const float hn  = o * tanhf_(cn);
                hp[ci] = hn;
                A_s[p ^ 1][row0 + r][u] = f2bf(hn);
            }
        }

        // stage x_{t+1} into A[p^1]; prefetch x_{t+2}
        if (tid < MROWS * 32) {
            const int row = tid >> 5, j = tid & 31;
            A_s[p ^ 1][row][UNITS + j] = f2bf(xr);
            if (t + 2 < T_STEPS)
                xr = x_dyn[((size_t)(b0 + row) * T_STEPS + (t + 2)) * 32 + j];
        }
    }

    #pragma unroll
    for (int h = 0; h < 2; ++h)
        #pragma unroll
        for (int r = 0; r < 2; ++r)
            out[(size_t)(b0 + row0 + r) * UNITS + (h ? u1 : u0)] = hp[h * 2 + r];
}

extern "C" void kernel_launch(void* const* d_in, const int* in_sizes, int n_in,
                              void* d_out, int out_size, void* d_ws, size_t ws_size,
                              hipStream_t stream) {
    const float* x_dyn  = (const float*)d_in[0];
    const float* x_sta  = (const float*)d_in[1];
    const float* w_ih   = (const float*)d_in[2];
    const float* w_hh   = (const float*)d_in[3];
    const float* w_sh   = (const float*)d_in[4];
    const float* bias   = (const float*)d_in[5];
    const float* bias_s = (const float*)d_in[6];
    float* out = (float*)d_out;
    unsigned short* wp = (unsigned short*)d_ws;   // 288*768*2 = 442 KB scratch

    pack_weights<<<(KTOT * G3 + 255) / 256, 256, 0, stream>>>(w_ih, w_hh, wp);
    lstm_mfma<<<NWGS, 512, 0, stream>>>(x_dyn, x_sta, wp, w_sh, bias, bias_s, out);
}